// Round 11
// baseline (266.885 us; speedup 1.0000x reference)
//
#include <hip/hip_runtime.h>

constexpr int   BATCH = 2;
constexpr int   NPTS  = 524288;            // P = 2^19
constexpr int   BINS  = 2048;              // BATCH * 32 * 32 tiles
constexpr int   CAP   = 768;               // per-bin capacity (mean 512, +11 sigma)
constexpr int   NBLK  = 512;               // persistent grid (2 blocks/CU x 256 CU)
constexpr float BETA  = 4.71238898038469f; // 1.5*pi
constexpr float PI_F  = 3.14159265358979f;

// LDS pad-16: breaks power-of-2 strides (butterflies + digit-rev readout)
#define PIDX(i) ((i) + ((i) >> 4))

// ---------------- workspace layout ----------------
// g    : 16 MB @ 0
// gcnt : 8 KB  @ 16 MB          (memset to 0 each call)
// bar  : 2 ints @ 16 MB + 8192  (memset to 0 each call)
// perm : BINS x CAP float4 records {x.x, x.y, gid, -} = 25.2 MB
constexpr size_t G_BYTES  = (size_t)BATCH * 1024 * 1024 * sizeof(float2);
constexpr size_t GCNT_OFF = G_BYTES;
constexpr size_t BAR_OFF  = G_BYTES + 8192;
constexpr size_t PERM_OFF = G_BYTES + 8192 + 64;

// LDS union (43128 B): [0, 34944) phase scratch; [34944, 43128) twiddle T
constexpr int SMEM_BYTES = 43128;
constexpr int T_F2_OFF   = 4368;           // float2 index of T

// i0(x) for x >= 3.75 (Numerical Recipes asymptotic, rel err ~1e-7)
__device__ __forceinline__ float i0f_large(float x) {
    float t = 3.75f / x;
    float p =  0.00392377f;
    p = p * t + -0.01647633f;
    p = p * t +  0.02635537f;
    p = p * t + -0.02057706f;
    p = p * t +  0.00916281f;
    p = p * t + -0.00157565f;
    p = p * t +  0.00225319f;
    p = p * t +  0.01328592f;
    p = p * t +  0.39894228f;
    return __expf(x) * rsqrtf(x) * p;
}

__device__ __forceinline__ int tile_of(float2 xv, int b) {
    int c1 = ((int)floorf(xv.x * 1024.0f)) & 1023;
    int c2 = ((int)floorf(xv.y * 1024.0f)) & 1023;
    return (b << 10) + ((c1 >> 5) << 5) + (c2 >> 5);
}

__device__ __forceinline__ float2 cmul(float2 a, float2 w) {
    return make_float2(a.x * w.x - a.y * w.y, a.x * w.y + a.y * w.x);
}

// Natural freq f -> storage position after radix-4 DIF (5 digit-reversed
// base-4 digits) = bit-reverse then swap bits within pairs.
__device__ __forceinline__ int digitrev4_10(int f) {
    unsigned r = __brev((unsigned)f) >> 22;
    return (int)(((r & 0x2AAu) >> 1) | ((r & 0x155u) << 1));
}

// Stage-concatenated radix-4 twiddles, 1023 float2:
// stage offsets: q=256 @0, q=64 @768, q=16 @960, q=4 @1008, q=1 @1020.
__device__ __forceinline__ void build_tw4(float2* T, int tid, int nthreads) {
    int off = 0, q = 256, sig = 1;
    #pragma unroll
    for (int st = 0; st < 5; ++st) {
        for (int m = tid; m < 3 * q; m += nthreads) {
            int sec = 0, j = m;
            if (j >= q) { sec++; j -= q; }
            if (j >= q) { sec++; j -= q; }
            float ang = (-2.0f * PI_F / 1024.0f) * (float)((sec + 1) * j * sig);
            float sw, cw;
            __sincosf(ang, &sw, &cw);
            T[off + m] = make_float2(cw, sw);
        }
        off += 3 * q; q >>= 2; sig <<= 2;
    }
}

// One radix-4 DIF butterfly at index bt for stage with quarter-stride q.
__device__ __forceinline__ void bfly4(float2* s, const float2* T,
                                      int bt, int q, int off) {
    int j    = bt & (q - 1);
    int base = ((bt - j) << 2) + j;        // (bt/q)*4q + j
    int p0 = PIDX(base), p1 = PIDX(base + q);
    int p2 = PIDX(base + 2 * q), p3 = PIDX(base + 3 * q);
    float2 a0 = s[p0], a1 = s[p1], a2 = s[p2], a3 = s[p3];
    float2 t0 = make_float2(a0.x + a2.x, a0.y + a2.y);
    float2 t1 = make_float2(a0.x - a2.x, a0.y - a2.y);
    float2 t2 = make_float2(a1.x + a3.x, a1.y + a3.y);
    float2 t3 = make_float2(a1.x - a3.x, a1.y - a3.y);
    float2 b0 = make_float2(t0.x + t2.x, t0.y + t2.y);
    float2 b2 = make_float2(t0.x - t2.x, t0.y - t2.y);
    float2 b1 = make_float2(t1.x + t3.y, t1.y - t3.x);   // t1 - i t3
    float2 b3 = make_float2(t1.x - t3.y, t1.y + t3.x);   // t1 + i t3
    s[p0] = b0;
    s[p1] = cmul(b1, T[off + j]);
    s[p2] = cmul(b2, T[off + q + j]);
    s[p3] = cmul(b3, T[off + 2 * q + j]);
}

// Grid barrier over NBLK co-resident blocks. Release/acquire fences handle
// cross-XCD L2 non-coherence (G16): threadfence = agent-scope wb/inv.
__device__ __forceinline__ void grid_barrier(int* ctr) {
    __syncthreads();
    if (threadIdx.x == 0) {
        __threadfence();                     // release prior writes
        atomicAdd(ctr, 1);
        while (atomicAdd(ctr, 0) < NBLK) __builtin_amdgcn_s_sleep(1);
        __threadfence();                     // acquire: invalidate stale lines
    }
    __syncthreads();
}

// ---- row FFT unit (radix-4) fused with deconvolution, 1 row ----
__device__ __forceinline__ void row_unit(int u, const float2* __restrict__ fh,
                                         float2* __restrict__ g,
                                         float2* s, const float2* T, int tid) {
    int blk = u & 511;                       // 0..511
    int b   = u >> 9;
    int row = (blk < 256) ? blk : blk + 512; // {0..255, 768..1023}
    int a1  = (row + 256) & 1023;            // fh row index, 0..511

    float k1 = (float)(a1 - 256);
    float w1 = (2.0f * PI_F / 1024.0f) * k1;
    float c1 = i0f_large(4.0f * sqrtf(BETA * BETA - w1 * w1));

    const float2* fr = fh + ((long)b << 18) + ((long)a1 << 9);

    float w2a = (2.0f * PI_F / 1024.0f) * (float)tid;
    float c2a = i0f_large(4.0f * sqrtf(BETA * BETA - w2a * w2a));
    float w2b = (2.0f * PI_F / 1024.0f) * (float)(tid - 256);
    float c2b = i0f_large(4.0f * sqrtf(BETA * BETA - w2b * w2b));

    float2 va = fr[tid + 256];
    float2 vb = fr[tid];
    float ia = 1.0f / (c1 * c2a);
    float ib = 1.0f / (c1 * c2b);
    float2 A = make_float2(va.x * ia, va.y * ia);   // idx tid
    float2 B = make_float2(vb.x * ib, vb.y * ib);   // idx tid+768

    __syncthreads();                          // WAR guard on s

    // stage q=256 in regs: {A,0,0,B} -> A+B, (A+iB)w1, (A-B)w2, (A-iB)w3
    s[PIDX(tid)]       = make_float2(A.x + B.x, A.y + B.y);
    s[PIDX(tid + 256)] = cmul(make_float2(A.x - B.y, A.y + B.x), T[tid]);
    s[PIDX(tid + 512)] = cmul(make_float2(A.x - B.x, A.y - B.y), T[256 + tid]);
    s[PIDX(tid + 768)] = cmul(make_float2(A.x + B.y, A.y - B.x), T[512 + tid]);

    int off = 768, q = 64;                    // stages q=64,16,4,1 in LDS
    #pragma unroll
    for (int st = 0; st < 4; ++st) {
        __syncthreads();
        bfly4(s, T, tid, q, off);
        off += 3 * q; q >>= 2;
    }
    __syncthreads();

    float2* base = g + ((long)b << 20) + ((long)row << 10);
    #pragma unroll
    for (int i = 0; i < 4; ++i) {
        int idx = tid + (i << 8);
        base[idx] = s[PIDX(digitrev4_10(idx))];
    }
}

// ---- binning unit: 2048 points, fat records {x, gid} ----
__device__ __forceinline__ void bin_unit(int u, const float2* __restrict__ x,
                                         int* __restrict__ gcnt,
                                         float4* __restrict__ perm,
                                         int* h, int tid) {
    __syncthreads();                         // WAR guard on smem
    for (int i = tid; i < BINS; i += 256) h[i] = 0;
    __syncthreads();

    int base = u * 2048;
    int    tile[8];
    float2 pv[8];
    #pragma unroll
    for (int i = 0; i < 8; ++i) {
        int gid = base + tid + i * 256;
        pv[i]   = x[gid];
        tile[i] = tile_of(pv[i], gid >> 19);
        atomicAdd(&h[tile[i]], 1);
    }
    __syncthreads();

    #pragma unroll
    for (int j = 0; j < 8; ++j) {
        int bi = tid + j * 256;
        int c  = h[bi];
        h[bi]  = c ? atomicAdd(&gcnt[bi], c) : 0;
    }
    __syncthreads();

    #pragma unroll
    for (int i = 0; i < 8; ++i) {
        int gid = base + tid + i * 256;
        int pos = atomicAdd(&h[tile[i]], 1);
        perm[tile[i] * CAP + pos] =
            make_float4(pv[i].x, pv[i].y, __int_as_float(gid), 0.0f);
    }
}

// ---- column FFT unit: 4 columns, stages q=256,64 in registers ----
__device__ __forceinline__ void cols_unit(int u, float2* __restrict__ g,
                                          float2* s, const float2* T, int t) {
    constexpr int STR = 1092;                // mod 16 = 4
    int b  = u >> 8;
    int C0 = (u & 255) * 4;
    int c  = t & 3, L = t >> 2;              // L in 0..63
    float2* gb = g + ((long)b << 20);

    float2 E[16];
    #pragma unroll
    for (int m = 0; m < 4; ++m) {            // rows 0..255
        int r = L + 64 * m;
        E[m] = gb[((long)r << 10) + C0 + c];
    }
    #pragma unroll
    for (int m = 12; m < 16; ++m) {          // rows 768..1023
        int r = L + 64 * m;
        E[m] = gb[((long)r << 10) + C0 + c];
    }

    // stage q=256: groups {m, m+4, m+8, m+12} = {A,0,0,B}
    #pragma unroll
    for (int m = 0; m < 4; ++m) {
        float2 A = E[m], B = E[m + 12];
        int j = L + 64 * m;
        E[m]      = make_float2(A.x + B.x, A.y + B.y);
        E[m + 4]  = cmul(make_float2(A.x - B.y, A.y + B.x), T[j]);
        E[m + 8]  = cmul(make_float2(A.x - B.x, A.y - B.y), T[256 + j]);
        E[m + 12] = cmul(make_float2(A.x + B.y, A.y - B.x), T[512 + j]);
    }

    // stage q=64: groups {4a+0..3}, j = L for all a
    {
        float2 u1 = T[768 + L], u2 = T[768 + 64 + L], u3 = T[768 + 128 + L];
        #pragma unroll
        for (int a = 0; a < 4; ++a) {
            float2 a0 = E[4*a], a1 = E[4*a+1], a2 = E[4*a+2], a3 = E[4*a+3];
            float2 t0 = make_float2(a0.x + a2.x, a0.y + a2.y);
            float2 t1 = make_float2(a0.x - a2.x, a0.y - a2.y);
            float2 t2 = make_float2(a1.x + a3.x, a1.y + a3.y);
            float2 t3 = make_float2(a1.x - a3.x, a1.y - a3.y);
            E[4*a]   = make_float2(t0.x + t2.x, t0.y + t2.y);
            E[4*a+1] = cmul(make_float2(t1.x + t3.y, t1.y - t3.x), u1);
            E[4*a+2] = cmul(make_float2(t0.x - t2.x, t0.y - t2.y), u2);
            E[4*a+3] = cmul(make_float2(t1.x - t3.y, t1.y + t3.x), u3);
        }
    }

    float2* sf = s + c * STR;
    #pragma unroll
    for (int m = 0; m < 16; ++m) sf[PIDX(L + 64 * m)] = E[m];

    int off = 960, q = 16;                   // stages q=16,4,1 in LDS
    #pragma unroll
    for (int st = 0; st < 3; ++st) {
        __syncthreads();
        #pragma unroll
        for (int rr = 0; rr < 4; ++rr)
            bfly4(sf, T, L + rr * 64, q, off);
        off += 3 * q; q >>= 2;
    }
    __syncthreads();

    #pragma unroll
    for (int i = 0; i < 16; ++i) {
        int r = L + i * 64;
        gb[((long)r << 10) + C0 + c] = sf[PIDX(digitrev4_10(r))];
    }
}

// ---- gather unit: one 32x32 tile, 6 taps/dim ----
__device__ __forceinline__ void gather_unit(int tb, const float2* __restrict__ g,
                                            const int* __restrict__ gcnt,
                                            const float4* __restrict__ perm,
                                            float2* __restrict__ out,
                                            float2* patch, int tid) {
    int b  = tb >> 10;
    int tt = tb & 1023;
    int tR = tt >> 5, tC = tt & 31;
    int R0 = (tR << 5) - 2, C0 = (tC << 5) - 2;
    const float2* gb = g + ((long)b << 20);

    __syncthreads();                         // WAR guard on patch
    for (int p = tid; p < 37 * 37; p += 256) {
        int pr = p / 37, pc = p - pr * 37;
        int gr = (R0 + pr) & 1023, gc = (C0 + pc) & 1023;
        patch[p] = gb[(gr << 10) + gc];
    }
    __syncthreads();

    int cnt = gcnt[tb];
    if (cnt > CAP) cnt = CAP;
    int off0 = tb * CAP;
    for (int i = tid; i < cnt; i += 256) {
        float4 rec = perm[off0 + i];
        int gid = __float_as_int(rec.z);

        float w1[6], w2[6];
        int rr0, cc0;
        {
            float xs = rec.x * 1024.0f;
            float fl = floorf(xs);
            float fr = xs - fl;
            rr0 = (((int)fl) & 1023) - (tR << 5);     // 0..31
            #pragma unroll
            for (int k = 0; k < 6; ++k) {
                float tv = fr - (float)(k - 2);       // |tv| < 3 -> u2 > 7
                float u2 = 16.0f - tv * tv;
                float ir = rsqrtf(u2);                // 1/u
                float z  = BETA * u2 * ir;            // beta*u in [12.5,18.9]
                w1[k] = __expf(z) * 0.159154943f * ir;   // sinh(z)/(pi*u)
            }
        }
        {
            float xs = rec.y * 1024.0f;
            float fl = floorf(xs);
            float fr = xs - fl;
            cc0 = (((int)fl) & 1023) - (tC << 5);     // 0..31
            #pragma unroll
            for (int k = 0; k < 6; ++k) {
                float tv = fr - (float)(k - 2);
                float u2 = 16.0f - tv * tv;
                float ir = rsqrtf(u2);
                float z  = BETA * u2 * ir;
                w2[k] = __expf(z) * 0.159154943f * ir;
            }
        }

        float ar = 0.0f, ai = 0.0f;
        #pragma unroll
        for (int ii = 0; ii < 6; ++ii) {
            int pbase = (rr0 + ii) * 37 + cc0;
            float wi = w1[ii];
            #pragma unroll
            for (int jj = 0; jj < 6; ++jj) {
                float2 gv = patch[pbase + jj];
                float w = wi * w2[jj];
                ar = fmaf(w, gv.x, ar);
                ai = fmaf(w, gv.y, ai);
            }
        }
        out[gid] = make_float2(ar, ai);
    }
}

// ---------------- persistent mega-kernel: 2 grid barriers ----------------
__global__ __launch_bounds__(256, 2) void mega(const float2* __restrict__ fh,
                                               float2* __restrict__ g,
                                               const float2* __restrict__ x,
                                               int* __restrict__ gcnt,
                                               float4* __restrict__ perm,
                                               float2* __restrict__ out,
                                               int* __restrict__ bar) {
    __shared__ __align__(16) char smem[SMEM_BYTES];
    float2* S = (float2*)smem;
    float2* T = (float2*)smem + T_F2_OFF;    // survives phases 1-2
    int tid = threadIdx.x, bid = blockIdx.x;

    build_tw4(T, tid, 256);
    __syncthreads();

    // phase 1: 2 row-FFT units + 1 binning unit per block
    row_unit(bid,        fh, g, S, T, tid);
    row_unit(bid + NBLK, fh, g, S, T, tid);
    bin_unit(bid, x, gcnt, perm, (int*)smem, tid);

    grid_barrier(&bar[0]);

    // phase 2: 1 column-FFT unit per block
    cols_unit(bid, g, S, T, tid);

    grid_barrier(&bar[1]);

    // phase 3: 4 gather tiles per block
    #pragma unroll
    for (int i = 0; i < 4; ++i)
        gather_unit(bid + i * NBLK, g, gcnt, perm, out, S, tid);
}

extern "C" void kernel_launch(void* const* d_in, const int* in_sizes, int n_in,
                              void* d_out, int out_size, void* d_ws, size_t ws_size,
                              hipStream_t stream) {
    const float2* x  = (const float2*)d_in[0];
    const float2* fh = (const float2*)d_in[1];
    char* ws = (char*)d_ws;
    float2* g    = (float2*)ws;
    int*    gcnt = (int*)(ws + GCNT_OFF);
    int*    bar  = (int*)(ws + BAR_OFF);
    float4* perm = (float4*)(ws + PERM_OFF);

    // zero gcnt + barrier counters (8256 B), then single persistent kernel
    hipMemsetAsync(gcnt, 0, 8192 + 64, stream);
    mega<<<dim3(NBLK), dim3(256), 0, stream>>>(fh, g, x, gcnt, perm,
                                               (float2*)d_out, bar);
}

// Round 12
// 117.120 us; speedup vs baseline: 2.2787x; 2.2787x over previous
//
#include <hip/hip_runtime.h>

constexpr int   BATCH = 2;
constexpr int   NPTS  = 524288;            // P = 2^19
constexpr int   BINS  = 2048;              // BATCH * 32 * 32 tiles
constexpr int   CAP   = 768;               // per-bin capacity (mean 512, +11 sigma)
constexpr float BETA  = 4.71238898038469f; // 1.5*pi
constexpr float PI_F  = 3.14159265358979f;

// LDS pad-16: breaks power-of-2 strides (butterflies + digit-rev readout)
#define PIDX(i) ((i) + ((i) >> 4))

// ---------------- workspace layout ----------------
// g    : 16 MB @ 0
// gcnt : 8 KB  @ 16 MB          (zeroed by block 0 of rows_and_bin)
// perm : BINS x CAP float4 records {x.x, x.y, gid, -} = 25.2 MB
constexpr size_t G_BYTES  = (size_t)BATCH * 1024 * 1024 * sizeof(float2);
constexpr size_t GCNT_OFF = G_BYTES;
constexpr size_t PERM_OFF = G_BYTES + 8192;

// i0(x) for x >= 3.75 (Numerical Recipes asymptotic, rel err ~1e-7)
__device__ __forceinline__ float i0f_large(float x) {
    float t = 3.75f / x;
    float p =  0.00392377f;
    p = p * t + -0.01647633f;
    p = p * t +  0.02635537f;
    p = p * t + -0.02057706f;
    p = p * t +  0.00916281f;
    p = p * t + -0.00157565f;
    p = p * t +  0.00225319f;
    p = p * t +  0.01328592f;
    p = p * t +  0.39894228f;
    return __expf(x) * rsqrtf(x) * p;
}

__device__ __forceinline__ int tile_of(float2 xv, int b) {
    int c1 = ((int)floorf(xv.x * 1024.0f)) & 1023;
    int c2 = ((int)floorf(xv.y * 1024.0f)) & 1023;
    return (b << 10) + ((c1 >> 5) << 5) + (c2 >> 5);
}

__device__ __forceinline__ float2 cmul(float2 a, float2 w) {
    return make_float2(a.x * w.x - a.y * w.y, a.x * w.y + a.y * w.x);
}

// Natural freq f -> storage position after radix-4 DIF (5 digit-reversed
// base-4 digits) = bit-reverse then swap bits within pairs.
__device__ __forceinline__ int digitrev4_10(int f) {
    unsigned r = __brev((unsigned)f) >> 22;
    return (int)(((r & 0x2AAu) >> 1) | ((r & 0x155u) << 1));
}

// Stage-concatenated radix-4 twiddles, 1023 float2:
// stage offsets: q=256 @0, q=64 @768, q=16 @960, q=4 @1008, q=1 @1020.
__device__ __forceinline__ void build_tw4(float2* T, int tid, int nthreads) {
    int off = 0, q = 256, sig = 1;
    #pragma unroll
    for (int st = 0; st < 5; ++st) {
        for (int m = tid; m < 3 * q; m += nthreads) {
            int sec = 0, j = m;
            if (j >= q) { sec++; j -= q; }
            if (j >= q) { sec++; j -= q; }
            float ang = (-2.0f * PI_F / 1024.0f) * (float)((sec + 1) * j * sig);
            float sw, cw;
            __sincosf(ang, &sw, &cw);
            T[off + m] = make_float2(cw, sw);
        }
        off += 3 * q; q >>= 2; sig <<= 2;
    }
}

// One radix-4 DIF butterfly at index bt for stage with quarter-stride q.
__device__ __forceinline__ void bfly4(float2* s, const float2* T,
                                      int bt, int q, int off) {
    int j    = bt & (q - 1);
    int base = ((bt - j) << 2) + j;        // (bt/q)*4q + j
    int p0 = PIDX(base), p1 = PIDX(base + q);
    int p2 = PIDX(base + 2 * q), p3 = PIDX(base + 3 * q);
    float2 a0 = s[p0], a1 = s[p1], a2 = s[p2], a3 = s[p3];
    float2 t0 = make_float2(a0.x + a2.x, a0.y + a2.y);
    float2 t1 = make_float2(a0.x - a2.x, a0.y - a2.y);
    float2 t2 = make_float2(a1.x + a3.x, a1.y + a3.y);
    float2 t3 = make_float2(a1.x - a3.x, a1.y - a3.y);
    float2 b0 = make_float2(t0.x + t2.x, t0.y + t2.y);
    float2 b2 = make_float2(t0.x - t2.x, t0.y - t2.y);
    float2 b1 = make_float2(t1.x + t3.y, t1.y - t3.x);   // t1 - i t3
    float2 b3 = make_float2(t1.x - t3.y, t1.y + t3.x);   // t1 + i t3
    s[p0] = b0;
    s[p1] = cmul(b1, T[off + j]);
    s[p2] = cmul(b2, T[off + q + j]);
    s[p3] = cmul(b3, T[off + 2 * q + j]);
}

// ---------------- fused: row FFTs (blocks 0..1023) + binning (1024..1279) ----
// Block 0 additionally zeroes gcnt via device-scope atomics at t~0. Bin
// blocks first do >=2us of point loads + LDS histogramming before touching
// gcnt, and the CP dispatches block 0 first -> ordering margin ~10x.
__global__ __launch_bounds__(256) void rows_and_bin(const float2* __restrict__ fh,
                                                    float2* __restrict__ g,
                                                    const float2* __restrict__ x,
                                                    int* __restrict__ gcnt,
                                                    float4* __restrict__ perm) {
    __shared__ __align__(16) char smem[16880];   // fft path: 1087+1023 float2
    int tid = threadIdx.x;

    if (blockIdx.x < 1024) {
        if (blockIdx.x == 0) {
            // zero the 2048 bin counters (replaces a whole memset dispatch)
            #pragma unroll
            for (int i = 0; i < 8; ++i)
                atomicExch(&gcnt[tid * 8 + i], 0);
        }
        // ---- row FFT fused with deconvolution (radix-4) ----
        float2* s = (float2*)smem;               // 1087
        float2* T = (float2*)smem + 1087;        // 1023
        int blk = blockIdx.x & 511;              // 0..511
        int b   = blockIdx.x >> 9;
        int row = (blk < 256) ? blk : blk + 512; // {0..255, 768..1023}
        int a1  = (row + 256) & 1023;            // fh row index, 0..511

        build_tw4(T, tid, 256);

        float k1 = (float)(a1 - 256);
        float w1 = (2.0f * PI_F / 1024.0f) * k1;
        float c1 = i0f_large(4.0f * sqrtf(BETA * BETA - w1 * w1));

        const float2* fr = fh + ((long)b << 18) + ((long)a1 << 9);

        float w2a = (2.0f * PI_F / 1024.0f) * (float)tid;
        float c2a = i0f_large(4.0f * sqrtf(BETA * BETA - w2a * w2a));
        float w2b = (2.0f * PI_F / 1024.0f) * (float)(tid - 256);
        float c2b = i0f_large(4.0f * sqrtf(BETA * BETA - w2b * w2b));

        float2 va = fr[tid + 256];
        float2 vb = fr[tid];
        float ia = 1.0f / (c1 * c2a);
        float ib = 1.0f / (c1 * c2b);
        float2 A = make_float2(va.x * ia, va.y * ia);   // idx tid
        float2 B = make_float2(vb.x * ib, vb.y * ib);   // idx tid+768

        __syncthreads();                          // T ready

        // stage q=256 in regs: {A,0,0,B} -> A+B, (A+iB)w1, (A-B)w2, (A-iB)w3
        s[PIDX(tid)]       = make_float2(A.x + B.x, A.y + B.y);
        s[PIDX(tid + 256)] = cmul(make_float2(A.x - B.y, A.y + B.x), T[tid]);
        s[PIDX(tid + 512)] = cmul(make_float2(A.x - B.x, A.y - B.y), T[256 + tid]);
        s[PIDX(tid + 768)] = cmul(make_float2(A.x + B.y, A.y - B.x), T[512 + tid]);

        int off = 768, q = 64;                    // stages q=64,16,4,1 in LDS
        #pragma unroll
        for (int st = 0; st < 4; ++st) {
            __syncthreads();
            bfly4(s, T, tid, q, off);
            off += 3 * q; q >>= 2;
        }
        __syncthreads();

        float2* base = g + ((long)b << 20) + ((long)row << 10);
        #pragma unroll
        for (int i = 0; i < 4; ++i) {
            int idx = tid + (i << 8);
            base[idx] = s[PIDX(digitrev4_10(idx))];
        }
    } else {
        // ---- binning: 4096 points per block, fat records {x, gid} ----
        int* h = (int*)smem;                     // 2048 ints
        int bblk = blockIdx.x - 1024;            // 0..255
        for (int i = tid; i < BINS; i += 256) h[i] = 0;
        __syncthreads();

        int base = bblk * 4096;
        int    tile[16];
        float2 pv[16];
        #pragma unroll
        for (int i = 0; i < 16; ++i) {
            int gid = base + tid + i * 256;
            pv[i]   = x[gid];
            tile[i] = tile_of(pv[i], gid >> 19);
            atomicAdd(&h[tile[i]], 1);
        }
        __syncthreads();

        #pragma unroll
        for (int j = 0; j < 8; ++j) {
            int bi = tid + j * 256;
            int c  = h[bi];
            h[bi]  = c ? atomicAdd(&gcnt[bi], c) : 0;
        }
        __syncthreads();

        #pragma unroll
        for (int i = 0; i < 16; ++i) {
            int gid = base + tid + i * 256;
            int pos = atomicAdd(&h[tile[i]], 1);
            perm[tile[i] * CAP + pos] =
                make_float4(pv[i].x, pv[i].y, __int_as_float(gid), 0.0f);
        }
    }
}

// Column FFTs (radix-4), 4 columns per block, 64 threads per FFT, 16
// elements/thread {L+64m}. Stages q=256,q=64 in REGISTERS; middle 512 rows
// are zero and never touch LDS. Stages q=16,4,1 in LDS.
__global__ __launch_bounds__(256) void fft_cols(float2* __restrict__ g) {
    constexpr int STR = 1092;                  // >= PIDX(1023)+1, mod 16 = 4
    __shared__ float2 s[4 * STR];              // ~35 KB
    __shared__ float2 T[1023];                 // 8 KB
    int b  = blockIdx.y;
    int C0 = blockIdx.x * 4;
    int t  = threadIdx.x;
    int c  = t & 3, L = t >> 2;                // L in 0..63
    float2* gb = g + ((long)b << 20);

    build_tw4(T, t, 256);

    float2 E[16];
    #pragma unroll
    for (int m = 0; m < 4; ++m) {              // rows 0..255
        int r = L + 64 * m;
        E[m] = gb[((long)r << 10) + C0 + c];
    }
    #pragma unroll
    for (int m = 12; m < 16; ++m) {            // rows 768..1023
        int r = L + 64 * m;
        E[m] = gb[((long)r << 10) + C0 + c];
    }
    __syncthreads();                           // T ready

    // stage q=256 in registers: groups {m, m+4, m+8, m+12} = {A,0,0,B}
    #pragma unroll
    for (int m = 0; m < 4; ++m) {
        float2 A = E[m], B = E[m + 12];
        int j = L + 64 * m;
        E[m]      = make_float2(A.x + B.x, A.y + B.y);
        E[m + 4]  = cmul(make_float2(A.x - B.y, A.y + B.x), T[j]);
        E[m + 8]  = cmul(make_float2(A.x - B.x, A.y - B.y), T[256 + j]);
        E[m + 12] = cmul(make_float2(A.x + B.y, A.y - B.x), T[512 + j]);
    }

    // stage q=64 in registers: groups {4a+0..3}, j = L for all a
    {
        float2 u1 = T[768 + L], u2 = T[768 + 64 + L], u3 = T[768 + 128 + L];
        #pragma unroll
        for (int a = 0; a < 4; ++a) {
            float2 a0 = E[4*a], a1 = E[4*a+1], a2 = E[4*a+2], a3 = E[4*a+3];
            float2 t0 = make_float2(a0.x + a2.x, a0.y + a2.y);
            float2 t1 = make_float2(a0.x - a2.x, a0.y - a2.y);
            float2 t2 = make_float2(a1.x + a3.x, a1.y + a3.y);
            float2 t3 = make_float2(a1.x - a3.x, a1.y - a3.y);
            E[4*a]   = make_float2(t0.x + t2.x, t0.y + t2.y);
            E[4*a+1] = cmul(make_float2(t1.x + t3.y, t1.y - t3.x), u1);
            E[4*a+2] = cmul(make_float2(t0.x - t2.x, t0.y - t2.y), u2);
            E[4*a+3] = cmul(make_float2(t1.x - t3.y, t1.y + t3.x), u3);
        }
    }

    float2* sf = s + c * STR;
    #pragma unroll
    for (int m = 0; m < 16; ++m) sf[PIDX(L + 64 * m)] = E[m];

    int off = 960, q = 16;                     // stages q=16,4,1 in LDS
    #pragma unroll
    for (int st = 0; st < 3; ++st) {
        __syncthreads();
        #pragma unroll
        for (int rr = 0; rr < 4; ++rr)
            bfly4(sf, T, L + rr * 64, q, off);
        off += 3 * q; q >>= 2;
    }
    __syncthreads();

    #pragma unroll
    for (int i = 0; i < 16; ++i) {
        int r = L + i * 64;
        gb[((long)r << 10) + C0 + c] = sf[PIDX(digitrev4_10(r))];
    }
}

// ---------------- binned gather, 6 taps/dim ----------------
// Weights via transcendentals (trans pipe overlaps LDS waits; LDS tables
// regressed in round 9). Points come from fat perm records (contiguous
// reads; no random x[] load). Patch 37x37 float2, stride 37 (odd).
__global__ __launch_bounds__(256) void gather_binned(const float2* __restrict__ g,
                                                     const int* __restrict__ gcnt,
                                                     const float4* __restrict__ perm,
                                                     float2* __restrict__ out) {
    __shared__ float2 patch[37 * 37];          // 10.9 KB
    int tb = blockIdx.x;           // 0..2047
    int b  = tb >> 10;
    int tt = tb & 1023;
    int tR = tt >> 5, tC = tt & 31;
    int R0 = (tR << 5) - 2, C0 = (tC << 5) - 2;
    const float2* gb = g + ((long)b << 20);

    for (int p = threadIdx.x; p < 37 * 37; p += 256) {
        int pr = p / 37, pc = p - pr * 37;
        int gr = (R0 + pr) & 1023, gc = (C0 + pc) & 1023;
        patch[p] = gb[(gr << 10) + gc];
    }
    __syncthreads();

    int cnt = gcnt[tb];
    if (cnt > CAP) cnt = CAP;
    int off0 = tb * CAP;
    for (int i = (int)threadIdx.x; i < cnt; i += 256) {
        float4 rec = perm[off0 + i];
        int gid = __float_as_int(rec.z);

        float w1[6], w2[6];
        int rr0, cc0;
        {
            float xs = rec.x * 1024.0f;
            float fl = floorf(xs);
            float fr = xs - fl;
            rr0 = (((int)fl) & 1023) - (tR << 5);     // 0..31
            #pragma unroll
            for (int k = 0; k < 6; ++k) {
                float tv = fr - (float)(k - 2);       // |tv| < 3 -> u2 > 7
                float u2 = 16.0f - tv * tv;
                float ir = rsqrtf(u2);                // 1/u
                float z  = BETA * u2 * ir;            // beta*u in [12.5,18.9]
                w1[k] = __expf(z) * 0.159154943f * ir;   // sinh(z)/(pi*u)
            }
        }
        {
            float xs = rec.y * 1024.0f;
            float fl = floorf(xs);
            float fr = xs - fl;
            cc0 = (((int)fl) & 1023) - (tC << 5);     // 0..31
            #pragma unroll
            for (int k = 0; k < 6; ++k) {
                float tv = fr - (float)(k - 2);
                float u2 = 16.0f - tv * tv;
                float ir = rsqrtf(u2);
                float z  = BETA * u2 * ir;
                w2[k] = __expf(z) * 0.159154943f * ir;
            }
        }

        float ar = 0.0f, ai = 0.0f;
        #pragma unroll
        for (int ii = 0; ii < 6; ++ii) {
            int pbase = (rr0 + ii) * 37 + cc0;
            float wi = w1[ii];
            #pragma unroll
            for (int jj = 0; jj < 6; ++jj) {
                float2 gv = patch[pbase + jj];
                float w = wi * w2[jj];
                ar = fmaf(w, gv.x, ar);
                ai = fmaf(w, gv.y, ai);
            }
        }
        out[gid] = make_float2(ar, ai);
    }
}

extern "C" void kernel_launch(void* const* d_in, const int* in_sizes, int n_in,
                              void* d_out, int out_size, void* d_ws, size_t ws_size,
                              hipStream_t stream) {
    const float2* x  = (const float2*)d_in[0];
    const float2* fh = (const float2*)d_in[1];
    char* ws = (char*)d_ws;
    float2* g    = (float2*)ws;
    int*    gcnt = (int*)(ws + GCNT_OFF);
    float4* perm = (float4*)(ws + PERM_OFF);

    rows_and_bin<<<dim3(1280), dim3(256), 0, stream>>>(fh, g, x, gcnt, perm);
    fft_cols    <<<dim3(256, BATCH), dim3(256), 0, stream>>>(g);

    gather_binned<<<dim3(BINS), dim3(256), 0, stream>>>(g, gcnt, perm, (float2*)d_out);
}

// Round 13
// 116.058 us; speedup vs baseline: 2.2996x; 1.0092x over previous
//
#include <hip/hip_runtime.h>

constexpr int   BATCH = 2;
constexpr int   NPTS  = 524288;            // P = 2^19
constexpr int   BINS  = 2048;              // BATCH * 32 * 32 tiles
constexpr int   CAP   = 768;               // per-bin capacity (mean 512, +11 sigma)
constexpr float BETA  = 4.71238898038469f; // 1.5*pi
constexpr float PI_F  = 3.14159265358979f;

typedef float v2f __attribute__((ext_vector_type(2)));

// LDS pad-16: breaks power-of-2 strides (butterflies + digit-rev readout)
#define PIDX(i) ((i) + ((i) >> 4))

// ---------------- workspace layout ----------------
// g    : 16 MB @ 0
// gcnt : 8 KB  @ 16 MB          (zeroed by block 0 of rows_and_bin)
// perm : BINS x CAP float4 records {x.x, x.y, gid, -} = 25.2 MB
constexpr size_t G_BYTES  = (size_t)BATCH * 1024 * 1024 * sizeof(v2f);
constexpr size_t GCNT_OFF = G_BYTES;
constexpr size_t PERM_OFF = G_BYTES + 8192;

// i0(x) for x >= 3.75 (Numerical Recipes asymptotic, rel err ~1e-7)
__device__ __forceinline__ float i0f_large(float x) {
    float t = 3.75f / x;
    float p =  0.00392377f;
    p = p * t + -0.01647633f;
    p = p * t +  0.02635537f;
    p = p * t + -0.02057706f;
    p = p * t +  0.00916281f;
    p = p * t + -0.00157565f;
    p = p * t +  0.00225319f;
    p = p * t +  0.01328592f;
    p = p * t +  0.39894228f;
    return __expf(x) * rsqrtf(x) * p;
}

__device__ __forceinline__ int tile_of(v2f xv, int b) {
    int c1 = ((int)floorf(xv.x * 1024.0f)) & 1023;
    int c2 = ((int)floorf(xv.y * 1024.0f)) & 1023;
    return (b << 10) + ((c1 >> 5) << 5) + (c2 >> 5);
}

// cmul via packed f32: T stores (c, s, -s, c); a*w = a.x*(c,s) + a.y*(-s,c)
__device__ __forceinline__ v2f cmul4(v2f a, float4 t) {
    v2f lo = {t.x, t.y}, hi = {t.z, t.w};
    return a.x * lo + a.y * hi;            // v_pk_mul + v_pk_fma
}
__device__ __forceinline__ v2f irot(v2f b) { return (v2f){-b.y, b.x}; }  // i*b

// Natural freq f -> storage position after radix-4 DIF (5 digit-reversed
// base-4 digits) = bit-reverse then swap bits within pairs. Involution.
__device__ __forceinline__ int digitrev4_10(int f) {
    unsigned r = __brev((unsigned)f) >> 22;
    return (int)(((r & 0x2AAu) >> 1) | ((r & 0x155u) << 1));
}

// Stage-concatenated radix-4 twiddles, 1023 float4 (c,s,-s,c):
// stage offsets: q=256 @0, q=64 @768, q=16 @960, q=4 @1008, q=1 @1020.
__device__ __forceinline__ void build_tw4(float4* T, int tid, int nthreads) {
    int off = 0, q = 256, sig = 1;
    #pragma unroll
    for (int st = 0; st < 5; ++st) {
        for (int m = tid; m < 3 * q; m += nthreads) {
            int sec = 0, j = m;
            if (j >= q) { sec++; j -= q; }
            if (j >= q) { sec++; j -= q; }
            float ang = (-2.0f * PI_F / 1024.0f) * (float)((sec + 1) * j * sig);
            float sw, cw;
            __sincosf(ang, &sw, &cw);
            T[off + m] = make_float4(cw, sw, -sw, cw);
        }
        off += 3 * q; q >>= 2; sig <<= 2;
    }
}

// One radix-4 DIF butterfly at index bt for stage with quarter-stride q.
__device__ __forceinline__ void bfly4(v2f* s, const float4* T,
                                      int bt, int q, int off) {
    int j    = bt & (q - 1);
    int base = ((bt - j) << 2) + j;        // (bt/q)*4q + j
    int p0 = PIDX(base), p1 = PIDX(base + q);
    int p2 = PIDX(base + 2 * q), p3 = PIDX(base + 3 * q);
    v2f a0 = s[p0], a1 = s[p1], a2 = s[p2], a3 = s[p3];
    v2f t0 = a0 + a2, t1 = a0 - a2, t2 = a1 + a3, t3 = a1 - a3;
    v2f r3 = irot(t3);
    s[p0] = t0 + t2;
    s[p1] = cmul4(t1 - r3, T[off + j]);
    s[p2] = cmul4(t0 - t2, T[off + q + j]);
    s[p3] = cmul4(t1 + r3, T[off + 2 * q + j]);
}

// ---------------- fused: row FFTs (blocks 0..1023) + binning (1024..1279) ----
// Block 0 additionally zeroes gcnt via device-scope atomics at t~0 (bin
// blocks do >=2us of loads+LDS histogram before touching gcnt).
__global__ __launch_bounds__(256) void rows_and_bin(const v2f* __restrict__ fh,
                                                    v2f* __restrict__ g,
                                                    const v2f* __restrict__ x,
                                                    int* __restrict__ gcnt,
                                                    float4* __restrict__ perm) {
    // fft path: s = 1088 v2f (8704 B, 16-aligned), T = 1023 float4 (16368 B)
    __shared__ __align__(16) char smem[25072];
    int tid = threadIdx.x;

    if (blockIdx.x < 1024) {
        if (blockIdx.x == 0) {
            #pragma unroll
            for (int i = 0; i < 8; ++i)
                atomicExch(&gcnt[tid * 8 + i], 0);
        }
        // ---- row FFT fused with deconvolution (radix-4) ----
        v2f*    s = (v2f*)smem;                  // 1087 used
        float4* T = (float4*)(smem + 8704);      // 1023
        int blk = blockIdx.x & 511;              // 0..511
        int b   = blockIdx.x >> 9;
        int row = (blk < 256) ? blk : blk + 512; // {0..255, 768..1023}
        int a1  = (row + 256) & 1023;            // fh row index, 0..511

        build_tw4(T, tid, 256);

        float k1 = (float)(a1 - 256);
        float w1 = (2.0f * PI_F / 1024.0f) * k1;
        float c1 = i0f_large(4.0f * sqrtf(BETA * BETA - w1 * w1));

        const v2f* fr = fh + ((long)b << 18) + ((long)a1 << 9);

        float w2a = (2.0f * PI_F / 1024.0f) * (float)tid;
        float c2a = i0f_large(4.0f * sqrtf(BETA * BETA - w2a * w2a));
        float w2b = (2.0f * PI_F / 1024.0f) * (float)(tid - 256);
        float c2b = i0f_large(4.0f * sqrtf(BETA * BETA - w2b * w2b));

        v2f A = fr[tid + 256] * (1.0f / (c1 * c2a));   // idx tid
        v2f B = fr[tid]       * (1.0f / (c1 * c2b));   // idx tid+768

        __syncthreads();                          // T ready

        // stage q=256 in regs: {A,0,0,B} -> A+B, (A+iB)w1, (A-B)w2, (A-iB)w3
        v2f rB = irot(B);
        s[PIDX(tid)]       = A + B;
        s[PIDX(tid + 256)] = cmul4(A + rB, T[tid]);
        s[PIDX(tid + 512)] = cmul4(A - B,  T[256 + tid]);
        s[PIDX(tid + 768)] = cmul4(A - rB, T[512 + tid]);

        int off = 768, q = 64;                    // stages q=64,16,4,1 in LDS
        #pragma unroll
        for (int st = 0; st < 4; ++st) {
            __syncthreads();
            bfly4(s, T, tid, q, off);
            off += 3 * q; q >>= 2;
        }
        __syncthreads();

        v2f* base = g + ((long)b << 20) + ((long)row << 10);
        #pragma unroll
        for (int i = 0; i < 4; ++i) {
            int idx = tid + (i << 8);
            base[idx] = s[PIDX(digitrev4_10(idx))];
        }
    } else {
        // ---- binning: 4096 points per block, fat records {x, gid} ----
        int* h = (int*)smem;                     // 2048 ints
        int bblk = blockIdx.x - 1024;            // 0..255
        for (int i = tid; i < BINS; i += 256) h[i] = 0;
        __syncthreads();

        int base = bblk * 4096;
        int tile[16];
        v2f pv[16];
        #pragma unroll
        for (int i = 0; i < 16; ++i) {
            int gid = base + tid + i * 256;
            pv[i]   = x[gid];
            tile[i] = tile_of(pv[i], gid >> 19);
            atomicAdd(&h[tile[i]], 1);
        }
        __syncthreads();

        #pragma unroll
        for (int j = 0; j < 8; ++j) {
            int bi = tid + j * 256;
            int c  = h[bi];
            h[bi]  = c ? atomicAdd(&gcnt[bi], c) : 0;
        }
        __syncthreads();

        #pragma unroll
        for (int i = 0; i < 16; ++i) {
            int gid = base + tid + i * 256;
            int pos = atomicAdd(&h[tile[i]], 1);
            perm[tile[i] * CAP + pos] =
                make_float4(pv[i].x, pv[i].y, __int_as_float(gid), 0.0f);
        }
    }
}

// Column FFTs (radix-4), 4 columns per block, 64 threads per FFT.
// Stages q=256,64 in registers; q=16 in LDS; q=4,1 in registers on a
// CONTIGUOUS padded chunk (PIDX(16L+j) = 17L+j), then direct digit-reversed
// global write (same 32B-segment coalescing as the old LDS readout).
__global__ __launch_bounds__(256) void fft_cols(v2f* __restrict__ g) {
    constexpr int STR = 1092;                  // >= PIDX(1023)+1, mod 16 = 4
    __shared__ v2f    s[4 * STR];              // ~35 KB
    __shared__ float4 T[1023];                 // 16 KB
    int b  = blockIdx.y;
    int C0 = blockIdx.x * 4;
    int t  = threadIdx.x;
    int c  = t & 3, L = t >> 2;                // L in 0..63
    v2f* gb = g + ((long)b << 20);

    build_tw4(T, t, 256);

    v2f E[16];
    #pragma unroll
    for (int m = 0; m < 4; ++m) {              // rows 0..255
        int r = L + 64 * m;
        E[m] = gb[((long)r << 10) + C0 + c];
    }
    #pragma unroll
    for (int m = 12; m < 16; ++m) {            // rows 768..1023
        int r = L + 64 * m;
        E[m] = gb[((long)r << 10) + C0 + c];
    }
    __syncthreads();                           // T ready

    // stage q=256 in registers: groups {m, m+4, m+8, m+12} = {A,0,0,B}
    #pragma unroll
    for (int m = 0; m < 4; ++m) {
        v2f A = E[m], B = E[m + 12];
        v2f rB = irot(B);
        int j = L + 64 * m;
        E[m]      = A + B;
        E[m + 4]  = cmul4(A + rB, T[j]);
        E[m + 8]  = cmul4(A - B,  T[256 + j]);
        E[m + 12] = cmul4(A - rB, T[512 + j]);
    }

    // stage q=64 in registers: groups {4a+0..3}, j = L for all a
    {
        float4 u1 = T[768 + L], u2 = T[768 + 64 + L], u3 = T[768 + 128 + L];
        #pragma unroll
        for (int a = 0; a < 4; ++a) {
            v2f a0 = E[4*a], a1 = E[4*a+1], a2 = E[4*a+2], a3 = E[4*a+3];
            v2f t0 = a0 + a2, t1 = a0 - a2, t2 = a1 + a3, t3 = a1 - a3;
            v2f r3 = irot(t3);
            E[4*a]   = t0 + t2;
            E[4*a+1] = cmul4(t1 - r3, u1);
            E[4*a+2] = cmul4(t0 - t2, u2);
            E[4*a+3] = cmul4(t1 + r3, u3);
        }
    }

    v2f* sf = s + c * STR;
    #pragma unroll
    for (int m = 0; m < 16; ++m) sf[PIDX(L + 64 * m)] = E[m];
    __syncthreads();

    // stage q=16 in LDS
    #pragma unroll
    for (int rr = 0; rr < 4; ++rr)
        bfly4(sf, T, L + rr * 64, 16, 960);
    __syncthreads();

    // contiguous chunk read (lane stride 17 v2f -> 2-way, free)
    v2f C[16];
    int cb = 17 * L;                           // PIDX(16L)
    #pragma unroll
    for (int j = 0; j < 16; ++j) C[j] = sf[cb + j];

    // stage q=4 in registers (off 1008)
    #pragma unroll
    for (int j = 0; j < 4; ++j) {
        v2f a0 = C[j], a1 = C[j+4], a2 = C[j+8], a3 = C[j+12];
        v2f t0 = a0 + a2, t1 = a0 - a2, t2 = a1 + a3, t3 = a1 - a3;
        v2f r3 = irot(t3);
        C[j]    = t0 + t2;
        C[j+4]  = cmul4(t1 - r3, T[1008 + j]);
        C[j+8]  = cmul4(t0 - t2, T[1012 + j]);
        C[j+12] = cmul4(t1 + r3, T[1016 + j]);
    }
    // stage q=1 in registers (twiddles identically 1)
    #pragma unroll
    for (int e = 0; e < 4; ++e) {
        v2f a0 = C[4*e], a1 = C[4*e+1], a2 = C[4*e+2], a3 = C[4*e+3];
        v2f t0 = a0 + a2, t1 = a0 - a2, t2 = a1 + a3, t3 = a1 - a3;
        v2f r3 = irot(t3);
        C[4*e]   = t0 + t2;
        C[4*e+1] = t1 - r3;
        C[4*e+2] = t0 - t2;
        C[4*e+3] = t1 + r3;
    }

    // direct digit-reversed write: element f=16L+j -> row digitrev(f)
    #pragma unroll
    for (int j = 0; j < 16; ++j) {
        int r = digitrev4_10((L << 4) + j);
        gb[((long)r << 10) + C0 + c] = C[j];
    }
}

// ---------------- binned gather, 6 taps/dim ----------------
// Weights via transcendentals (trans pipe overlaps LDS waits; LDS tables
// regressed in round 9). Points from fat perm records. Patch 37x37 v2f.
__global__ __launch_bounds__(256) void gather_binned(const v2f* __restrict__ g,
                                                     const int* __restrict__ gcnt,
                                                     const float4* __restrict__ perm,
                                                     v2f* __restrict__ out) {
    __shared__ v2f patch[37 * 37];             // 10.9 KB
    int tb = blockIdx.x;           // 0..2047
    int b  = tb >> 10;
    int tt = tb & 1023;
    int tR = tt >> 5, tC = tt & 31;
    int R0 = (tR << 5) - 2, C0 = (tC << 5) - 2;
    const v2f* gb = g + ((long)b << 20);

    for (int p = threadIdx.x; p < 37 * 37; p += 256) {
        int pr = p / 37, pc = p - pr * 37;
        int gr = (R0 + pr) & 1023, gc = (C0 + pc) & 1023;
        patch[p] = gb[(gr << 10) + gc];
    }
    __syncthreads();

    int cnt = gcnt[tb];
    if (cnt > CAP) cnt = CAP;
    int off0 = tb * CAP;
    for (int i = (int)threadIdx.x; i < cnt; i += 256) {
        float4 rec = perm[off0 + i];
        int gid = __float_as_int(rec.z);

        float w1[6], w2[6];
        int rr0, cc0;
        {
            float xs = rec.x * 1024.0f;
            float fl = floorf(xs);
            float fr = xs - fl;
            rr0 = (((int)fl) & 1023) - (tR << 5);     // 0..31
            #pragma unroll
            for (int k = 0; k < 6; ++k) {
                float tv = fr - (float)(k - 2);       // |tv| < 3 -> u2 > 7
                float u2 = 16.0f - tv * tv;
                float ir = rsqrtf(u2);                // 1/u
                float z  = BETA * u2 * ir;            // beta*u in [12.5,18.9]
                w1[k] = __expf(z) * 0.159154943f * ir;   // sinh(z)/(pi*u)
            }
        }
        {
            float xs = rec.y * 1024.0f;
            float fl = floorf(xs);
            float fr = xs - fl;
            cc0 = (((int)fl) & 1023) - (tC << 5);     // 0..31
            #pragma unroll
            for (int k = 0; k < 6; ++k) {
                float tv = fr - (float)(k - 2);
                float u2 = 16.0f - tv * tv;
                float ir = rsqrtf(u2);
                float z  = BETA * u2 * ir;
                w2[k] = __expf(z) * 0.159154943f * ir;
            }
        }

        v2f acc = {0.0f, 0.0f};
        #pragma unroll
        for (int ii = 0; ii < 6; ++ii) {
            int pbase = (rr0 + ii) * 37 + cc0;
            float wi = w1[ii];
            #pragma unroll
            for (int jj = 0; jj < 6; ++jj)
                acc += (wi * w2[jj]) * patch[pbase + jj];   // v_pk_fma_f32
        }
        out[gid] = acc;
    }
}

extern "C" void kernel_launch(void* const* d_in, const int* in_sizes, int n_in,
                              void* d_out, int out_size, void* d_ws, size_t ws_size,
                              hipStream_t stream) {
    const v2f* x  = (const v2f*)d_in[0];
    const v2f* fh = (const v2f*)d_in[1];
    char* ws = (char*)d_ws;
    v2f*    g    = (v2f*)ws;
    int*    gcnt = (int*)(ws + GCNT_OFF);
    float4* perm = (float4*)(ws + PERM_OFF);

    rows_and_bin<<<dim3(1280), dim3(256), 0, stream>>>(fh, g, x, gcnt, perm);
    fft_cols    <<<dim3(256, BATCH), dim3(256), 0, stream>>>(g);

    gather_binned<<<dim3(BINS), dim3(256), 0, stream>>>(g, gcnt, perm, (v2f*)d_out);
}